// Round 5
// baseline (169.057 us; speedup 1.0000x reference)
//
#include <hip/hip_runtime.h>

#define NPTS   32768
#define NCODES 1024
#define DIM    256
#define HWSZ   1024
#define CHW    (DIM*HWSZ)      // 262144
#define QSZ    8388608         // B*C*H*W

typedef __attribute__((ext_vector_type(8))) short short8;   // 8 bf16 = 4 VGPRs
typedef __attribute__((ext_vector_type(4))) float f32x4;

// async global->LDS, 16B per lane; dest = wave-uniform base + lane*16
__device__ __forceinline__ void gload16(const void* g, void* l) {
    __builtin_amdgcn_global_load_lds((const __attribute__((address_space(1))) void*)g,
                                     (__attribute__((address_space(3))) void*)l,
                                     16, 0, 0);
}

__device__ __forceinline__ unsigned bf16_rne(float f) {
    unsigned u = __float_as_uint(f);
    return (u + 0x7fffu + ((u >> 16) & 1u)) >> 16;
}

// pack (dist, code) into a monotone u64 key: smaller dist first, then smaller code.
__device__ __forceinline__ unsigned long long pack_di(float d, int code) {
    unsigned u = __float_as_uint(d);
    unsigned key = u ^ ((unsigned)((int)u >> 31) | 0x80000000u);
    return ((unsigned long long)key << 32) | (unsigned)code;
}

// ---- fused prep: blocks 0..2047 = z -> Xh/Xl transpose+split (c-half per block);
//                  blocks 2048..2303 = emb -> Eh/El + e2, plus win[] init ----
__global__ void k_prep(const float* __restrict__ z, const float* __restrict__ emb,
                       short* __restrict__ Xh, short* __restrict__ Xl,
                       short* __restrict__ Eh, short* __restrict__ El,
                       float* __restrict__ e2, unsigned long long* __restrict__ win) {
    int tid = threadIdx.x;
    if (blockIdx.x >= 2048) {
        int eb = blockIdx.x - 2048;
        // init packed-argmin array (runs before k_dist by stream order)
        int widx = eb * 256 + tid;
        if (widx < NPTS) win[widx] = ~0ull;
        // --- emb row -> Eh/El bf16 split + e2 (fp64). 1 wave per row. ---
        int lane = tid & 63, w = tid >> 6;
        int k = eb * 4 + w;
        const float4 v = *reinterpret_cast<const float4*>(emb + k * DIM + lane * 4);
        float f[4] = {v.x, v.y, v.z, v.w};
        short h[4], l[4];
        double s = 0.0;
        #pragma unroll
        for (int i = 0; i < 4; ++i) {
            unsigned hb = bf16_rne(f[i]);
            float hf = __uint_as_float(hb << 16);
            h[i] = (short)hb;
            l[i] = (short)bf16_rne(f[i] - hf);
            s += (double)f[i] * f[i];
        }
        *reinterpret_cast<short4*>(Eh + k * DIM + lane * 4) = make_short4(h[0], h[1], h[2], h[3]);
        *reinterpret_cast<short4*>(El + k * DIM + lane * 4) = make_short4(l[0], l[1], l[2], l[3]);
        #pragma unroll
        for (int m = 32; m >= 1; m >>= 1) s += __shfl_xor(s, m);
        if (lane == 0) e2[k] = (float)s;
        return;
    }
    // --- z (b,c,hw) -> Xh/Xl row-major (n,c) bf16 hi/lo; 16B stores ---
    __shared__ float T[64][33];          // [c_local][hw_local], pad: <=2-way banks
    int blk = blockIdx.x;
    int b   = blk >> 6;
    int rem = blk & 63;
    int ht  = rem >> 1;
    int ch  = rem & 1;                   // c-half: cc in {2ch, 2ch+1}
    int hw0 = ht * 32;
    int n0  = b * HWSZ + hw0;
    int hq = tid & 7, cr = tid >> 3;     // read map: 32 c-rows x 8 float4 lanes
    int wp = tid >> 3, wc = tid & 7;     // write map: 32 points x 8 channel-octets
    const float* zp = z + b * CHW;
    #pragma unroll
    for (int cc2 = 0; cc2 < 2; ++cc2) {
        int c0 = (ch * 2 + cc2) * 64;
        if (cc2) __syncthreads();
        #pragma unroll
        for (int p = 0; p < 2; ++p) {
            int c = p * 32 + cr;
            float4 v = *reinterpret_cast<const float4*>(zp + (c0 + c) * HWSZ + hw0 + hq * 4);
            T[c][hq * 4 + 0] = v.x; T[c][hq * 4 + 1] = v.y;
            T[c][hq * 4 + 2] = v.z; T[c][hq * 4 + 3] = v.w;
        }
        __syncthreads();
        short8 hv, lv;
        #pragma unroll
        for (int k = 0; k < 8; ++k) {
            float f = T[wc * 8 + k][wp];
            unsigned hb = bf16_rne(f);
            float hf = __uint_as_float(hb << 16);
            hv[k] = (short)hb;
            lv[k] = (short)bf16_rne(f - hf);
        }
        *reinterpret_cast<short8*>(Xh + (n0 + wp) * DIM + c0 + wc * 8) = hv;
        *reinterpret_cast<short8*>(Xl + (n0 + wp) * DIM + c0 + wc * 8) = lv;
    }
}

// ---- fused split-bf16 MFMA distance GEMM + argmin over a 128-code tile ----
// Round-10: A-only double-buffer + counted vmcnt. A (Xh/Xl, 33MB L3/HBM
// stream, ~400-900cy) is the long-pole load; B (Eh/El, 2MB, L2-hot, ~200cy)
// is short. Per step: s_barrier -> issue B(t)+A(t+1) -> vmcnt(4) [A(t),B(t)
// done; A(t+1)'s 4 loads fly through the MFMA cluster] -> s_barrier ->
// ds_read -> 48 MFMA. LDS 49.3KB keeps 3 blocks/CU (the variable that killed
// R6's full double-buffer at 67KB). Barrier mechanics proven correct in R6.
// grid 2048: pt = blk&255, ct = blk>>8 -> 8 ct-blocks of a pt share blk%8 (XCD).
__launch_bounds__(256, 3)
__global__ void k_dist(const short* __restrict__ Xh, const short* __restrict__ Xl,
                       const short* __restrict__ Eh, const short* __restrict__ El,
                       const float* __restrict__ e2, unsigned long long* __restrict__ win) {
    __shared__ __align__(16) short Ah[2][4096];   // [buf][128 pts][32 k] (swizzled quads)
    __shared__ __align__(16) short Al[2][4096];
    __shared__ __align__(16) short Bh[4096];      // [128 codes][32 k]
    __shared__ __align__(16) short Bl[4096];
    __shared__ float sv[2][128];
    __shared__ int   si[2][128];

    const int tid = threadIdx.x;
    const int pt = blockIdx.x & 255;
    const int ct = blockIdx.x >> 8;
    const int n0 = pt * 128;
    const int c0 = ct * 128;

    const int w = tid >> 6, lane = tid & 63;
    const int wr = w >> 1, wc = w & 1;              // wave covers pts wr*64, codes wc*64
    const int m16 = lane & 15, quad = lane >> 4;

    f32x4 acc[4][4];
    #pragma unroll
    for (int i = 0; i < 4; ++i)
        #pragma unroll
        for (int j = 0; j < 4; ++j) acc[i][j] = (f32x4){0.f, 0.f, 0.f, 0.f};

    // staging: each gload16 stages 16 rows x 64B = 1KB per wave.
    // lane -> (row r = lane>>2, phys k-quad = lane&3); swizzle key s = (r>>1)&3
    // = (lane>>3)&3; this phys quad holds source logical quad (q - s) & 3.
    const int r   = lane >> 2;
    const int swz = (((lane & 3) - ((lane >> 3) & 3)) & 3) * 8;  // shorts
    const int ldsoff0 = (w * 16) * 64;        // bytes; rows w*16..
    const int ldsoff1 = (64 + w * 16) * 64;   // rows 64+w*16..
    const int arow0 = (n0 + w * 16 + r) * DIM;
    const int arow1 = (n0 + 64 + w * 16 + r) * DIM;
    const int brow0 = (c0 + w * 16 + r) * DIM;
    const int brow1 = (c0 + 64 + w * 16 + r) * DIM;

    // frag-read swizzle: phys quad = (quad + (m16>>1)) & 3  (row = i*16+m16)
    const int pq = ((quad + (m16 >> 1)) & 3) * 8;

    // 4 gload16 per A-stage, 4 per B-stage (per wave) -> vmcnt counts these.
    #define STAGE_A(buf, t) do {                                      \
        const int ka_ = (t) * 32 + swz;                               \
        gload16(Xh + arow0 + ka_, (char*)Ah[buf] + ldsoff0);          \
        gload16(Xh + arow1 + ka_, (char*)Ah[buf] + ldsoff1);          \
        gload16(Xl + arow0 + ka_, (char*)Al[buf] + ldsoff0);          \
        gload16(Xl + arow1 + ka_, (char*)Al[buf] + ldsoff1);          \
    } while (0)
    #define STAGE_B(t) do {                                           \
        const int kb_ = (t) * 32 + swz;                               \
        gload16(Eh + brow0 + kb_, (char*)Bh + ldsoff0);               \
        gload16(Eh + brow1 + kb_, (char*)Bh + ldsoff1);               \
        gload16(El + brow0 + kb_, (char*)Bl + ldsoff0);               \
        gload16(El + brow1 + kb_, (char*)Bl + ldsoff1);               \
    } while (0)

    STAGE_A(0, 0);                               // prologue: A(0) in flight

    for (int t = 0; t < 8; ++t) {
        const int cur = t & 1;
        // (1) all waves consumed step t-1 frags -> Bh/Bl and Ah[cur^1] free
        __builtin_amdgcn_s_barrier();
        STAGE_B(t);                              // 4 loads (oldest after A(t))
        if (t < 7) STAGE_A(cur ^ 1, t + 1);      // 4 newest: fly through MFMA
        // A(t)+B(t) complete; A(t+1) stays in flight (never drain to 0 mid-loop)
        if (t < 7) asm volatile("s_waitcnt vmcnt(4)" ::: "memory");
        else       asm volatile("s_waitcnt vmcnt(0)" ::: "memory");
        __builtin_amdgcn_s_barrier();            // (2) tile t fully staged by all waves
        __builtin_amdgcn_sched_barrier(0);

        short8 ah[4], al[4], bh[4], bl[4];
        const short* Ahc = Ah[cur]; const short* Alc = Al[cur];
        #pragma unroll
        for (int i = 0; i < 4; ++i) {
            int ar = (wr * 64 + i * 16 + m16) * 32 + pq;
            ah[i] = *(const short8*)&Ahc[ar];
            al[i] = *(const short8*)&Alc[ar];
        }
        #pragma unroll
        for (int j = 0; j < 4; ++j) {
            int br = (wc * 64 + j * 16 + m16) * 32 + pq;
            bh[j] = *(const short8*)&Bh[br];
            bl[j] = *(const short8*)&Bl[br];
        }
        #pragma unroll
        for (int i = 0; i < 4; ++i)
            #pragma unroll
            for (int j = 0; j < 4; ++j)
                acc[i][j] = __builtin_amdgcn_mfma_f32_16x16x32_bf16(ah[i], bh[j], acc[i][j], 0, 0, 0);
        #pragma unroll
        for (int i = 0; i < 4; ++i)
            #pragma unroll
            for (int j = 0; j < 4; ++j)
                acc[i][j] = __builtin_amdgcn_mfma_f32_16x16x32_bf16(al[i], bh[j], acc[i][j], 0, 0, 0);
        #pragma unroll
        for (int i = 0; i < 4; ++i)
            #pragma unroll
            for (int j = 0; j < 4; ++j)
                acc[i][j] = __builtin_amdgcn_mfma_f32_16x16x32_bf16(ah[i], bl[j], acc[i][j], 0, 0, 0);
    }
    #undef STAGE_A
    #undef STAGE_B

    // dist = e2[code] - 2*dot ; C/D layout: col=lane&15 (code), row=quad*4+reg (pt)
    float ecol[4];
    #pragma unroll
    for (int j = 0; j < 4; ++j) ecol[j] = e2[c0 + wc * 64 + j * 16 + m16];

    #pragma unroll
    for (int i = 0; i < 4; ++i) {
        #pragma unroll
        for (int rr = 0; rr < 4; ++rr) {
            float best = 3.4e38f; int bi = 0;
            #pragma unroll
            for (int j = 0; j < 4; ++j) {           // j ascending -> code ascending
                float d = fmaf(-2.f, acc[i][j][rr], ecol[j]);
                int code = c0 + wc * 64 + j * 16 + m16;
                if (d < best) { best = d; bi = code; }
            }
            #pragma unroll
            for (int m = 1; m < 16; m <<= 1) {      // 16 lanes hold 16 codes of this pt
                float ov = __shfl_xor(best, m);
                int   oi = __shfl_xor(bi, m);
                if (ov < best || (ov == best && oi < bi)) { best = ov; bi = oi; }
            }
            if (m16 == 0) {
                int p = wr * 64 + i * 16 + quad * 4 + rr;
                sv[wc][p] = best; si[wc][p] = bi;
            }
        }
    }
    __syncthreads();
    if (tid < 128) {
        float v0 = sv[0][tid]; int i0 = si[0][tid];
        float v1 = sv[1][tid]; int i1 = si[1][tid];
        if (v1 < v0) { v0 = v1; i0 = i1; }          // tie -> wc0 = smaller codes
        atomicMin(win + n0 + tid, pack_di(v0, i0)); // global argmin, no round-trip
    }
}

// ---- output: gather winner rows + write q/st/idx. grid 2048 (c-half split). ----
__global__ void k_out(const float* __restrict__ z, const float* __restrict__ emb,
                      const unsigned long long* __restrict__ win,
                      float* __restrict__ out) {
    __shared__ float Q[32][129];                    // [hw_local][c_half], 16.5KB
    __shared__ int sbi[32];
    int blk = blockIdx.x;
    int n0 = (blk >> 1) * 32;
    int ch = blk & 1;                               // c in [ch*128, ch*128+128)
    int tid = threadIdx.x;
    if (tid < 32) {
        int n = n0 + tid;
        int bi = (int)(unsigned)(win[n] & 0xFFFFFFFFull);
        sbi[tid] = bi;
        if (ch == 0) out[2 * QSZ + n] = (float)bi;  // idx as float
    }
    __syncthreads();
    {   // gather: 8 lanes x float4 x 4 j cover the 512B half-row per point
        int pt = tid >> 3, co = tid & 7;
        const float* ep = emb + sbi[pt] * DIM + ch * 128;
        #pragma unroll
        for (int j = 0; j < 4; ++j) {
            int c = j * 32 + co * 4;
            float4 v = *reinterpret_cast<const float4*>(ep + c);
            Q[pt][c] = v.x; Q[pt][c + 1] = v.y; Q[pt][c + 2] = v.z; Q[pt][c + 3] = v.w;
        }
    }
    __syncthreads();
    int hq = tid & 7, cr = tid >> 3;                // 8x16B = 128B runs per c-row
    int b = n0 >> 10, hw0 = (n0 & 1023) + hq * 4;
    #pragma unroll
    for (int it = 0; it < 4; ++it) {
        int cl = it * 32 + cr;                      // local c within half
        int c  = ch * 128 + cl;
        int off = b * CHW + c * HWSZ + hw0;
        float4 zv = *reinterpret_cast<const float4*>(z + off);
        float4 q = make_float4(Q[hq * 4 + 0][cl], Q[hq * 4 + 1][cl],
                               Q[hq * 4 + 2][cl], Q[hq * 4 + 3][cl]);
        *reinterpret_cast<float4*>(out + off) = q;
        float4 st = make_float4((q.x - zv.x) + zv.x, (q.y - zv.y) + zv.y,
                                (q.z - zv.z) + zv.z, (q.w - zv.w) + zv.w);
        *reinterpret_cast<float4*>(out + QSZ + off) = st;
    }
}

extern "C" void kernel_launch(void* const* d_in, const int* in_sizes, int n_in,
                              void* d_out, int out_size, void* d_ws, size_t ws_size,
                              hipStream_t stream) {
    const float* z   = (const float*)d_in[0];
    const float* emb = (const float*)d_in[1];
    float* out = (float*)d_out;
    float* ws  = (float*)d_ws;

    // ws layout (floats): Eh[0,131072) El[131072,262144) e2[262144,263168)
    //                     win[263168, 263168+65536) as u64 (256KB, 8B-aligned)
    short* Eh   = (short*)ws;
    short* El   = (short*)(ws + 131072);
    float* e2   = ws + 262144;
    unsigned long long* win = (unsigned long long*)(ws + 263168);

    // big X arrays live in d_out's q/st region (fully overwritten by k_out later)
    short* Xh = (short*)out;                 // 16.8 MB
    short* Xl = (short*)(out + 4194304);     // 16.8 MB

    hipLaunchKernelGGL(k_prep, dim3(2304), dim3(256), 0, stream, z, emb, Xh, Xl, Eh, El, e2, win);
    hipLaunchKernelGGL(k_dist, dim3(2048), dim3(256), 0, stream, Xh, Xl, Eh, El, e2, win);
    hipLaunchKernelGGL(k_out,  dim3(2048), dim3(256), 0, stream, z, emb, win, out);
}

// Round 6
// 163.275 us; speedup vs baseline: 1.0354x; 1.0354x over previous
//
#include <hip/hip_runtime.h>

#define NPTS   32768
#define NCODES 1024
#define DIM    256
#define HWSZ   1024
#define CHW    (DIM*HWSZ)      // 262144
#define QSZ    8388608         // B*C*H*W

typedef __attribute__((ext_vector_type(8))) short short8;   // 8 bf16 = 4 VGPRs
typedef __attribute__((ext_vector_type(4))) float f32x4;

__device__ __forceinline__ unsigned bf16_rne(float f) {
    unsigned u = __float_as_uint(f);
    return (u + 0x7fffu + ((u >> 16) & 1u)) >> 16;
}

// pack (dist, code) into a monotone u64 key: smaller dist first, then smaller code.
__device__ __forceinline__ unsigned long long pack_di(float d, int code) {
    unsigned u = __float_as_uint(d);
    unsigned key = u ^ ((unsigned)((int)u >> 31) | 0x80000000u);
    return ((unsigned long long)key << 32) | (unsigned)code;
}

// Frag-major layout: element (row n, chan c) lives at
//   [n>>7][(n>>6)&1][c>>5][(n>>4)&3][(c>>3)&3][n&15][c&7]
// so an MFMA frag (fixed n-block, t, i) is one contiguous 1KB run with
// lane (m16,quad) at base + lane*16B. Same formula serves X (n<32768)
// and E (n<1024). 100% cache-line utilization on frag loads (R7's 4x
// over-fetch was 16B-used-per-64B-line; this fixes it).
__device__ __forceinline__ int fmoff(int n, int c) {
    return ((((((n >> 7) * 2 + ((n >> 6) & 1)) * 8 + (c >> 5)) * 4 + ((n >> 4) & 3)) * 4
             + ((c >> 3) & 3)) * 16 + (n & 15)) * 8 + (c & 7);
}

// ---- fused prep: blocks 0..2047 = z -> Xh/Xl transpose+split (c-half per block);
//                  blocks 2048..2303 = emb -> Eh/El + e2, plus win[] init ----
__global__ void k_prep(const float* __restrict__ z, const float* __restrict__ emb,
                       short* __restrict__ Xh, short* __restrict__ Xl,
                       short* __restrict__ Eh, short* __restrict__ El,
                       float* __restrict__ e2, unsigned long long* __restrict__ win) {
    int tid = threadIdx.x;
    if (blockIdx.x >= 2048) {
        int eb = blockIdx.x - 2048;
        // init packed-argmin array (runs before k_dist by stream order)
        int widx = eb * 256 + tid;
        if (widx < NPTS) win[widx] = ~0ull;
        // --- emb row -> Eh/El bf16 split + e2 (fp64). 1 wave per row. ---
        int lane = tid & 63, w = tid >> 6;
        int k = eb * 4 + w;
        const float4 v = *reinterpret_cast<const float4*>(emb + k * DIM + lane * 4);
        float f[4] = {v.x, v.y, v.z, v.w};
        short h[4], l[4];
        double s = 0.0;
        #pragma unroll
        for (int i = 0; i < 4; ++i) {
            unsigned hb = bf16_rne(f[i]);
            float hf = __uint_as_float(hb << 16);
            h[i] = (short)hb;
            l[i] = (short)bf16_rne(f[i] - hf);
            s += (double)f[i] * f[i];
        }
        int eoff = fmoff(k, lane * 4);     // (c&7) in {0,4} -> 8B-aligned
        *reinterpret_cast<short4*>(Eh + eoff) = make_short4(h[0], h[1], h[2], h[3]);
        *reinterpret_cast<short4*>(El + eoff) = make_short4(l[0], l[1], l[2], l[3]);
        #pragma unroll
        for (int m = 32; m >= 1; m >>= 1) s += __shfl_xor(s, m);
        if (lane == 0) e2[k] = (float)s;
        return;
    }
    // --- z (b,c,hw) -> Xh/Xl frag-major bf16 hi/lo; 16B stores ---
    __shared__ float T[64][33];          // [c_local][hw_local], pad: <=2-way banks
    int blk = blockIdx.x;
    int b   = blk >> 6;
    int rem = blk & 63;
    int ht  = rem >> 1;
    int ch  = rem & 1;                   // c-half: cc in {2ch, 2ch+1}
    int hw0 = ht * 32;
    int n0  = b * HWSZ + hw0;
    int hq = tid & 7, cr = tid >> 3;     // read map: 32 c-rows x 8 float4 lanes
    int wp = tid >> 3, wc = tid & 7;     // write map: 32 points x 8 channel-octets
    const float* zp = z + b * CHW;
    #pragma unroll
    for (int cc2 = 0; cc2 < 2; ++cc2) {
        int c0 = (ch * 2 + cc2) * 64;
        if (cc2) __syncthreads();
        #pragma unroll
        for (int p = 0; p < 2; ++p) {
            int c = p * 32 + cr;
            float4 v = *reinterpret_cast<const float4*>(zp + (c0 + c) * HWSZ + hw0 + hq * 4);
            T[c][hq * 4 + 0] = v.x; T[c][hq * 4 + 1] = v.y;
            T[c][hq * 4 + 2] = v.z; T[c][hq * 4 + 3] = v.w;
        }
        __syncthreads();
        short8 hv, lv;
        #pragma unroll
        for (int k = 0; k < 8; ++k) {
            float f = T[wc * 8 + k][wp];
            unsigned hb = bf16_rne(f);
            float hf = __uint_as_float(hb << 16);
            hv[k] = (short)hb;
            lv[k] = (short)bf16_rne(f - hf);
        }
        int off = fmoff(n0 + wp, c0 + wc * 8);   // octet-aligned -> 16B store
        *reinterpret_cast<short8*>(Xh + off) = hv;
        *reinterpret_cast<short8*>(Xl + off) = lv;
    }
}

// ---- zero-LDS frag-major split-bf16 MFMA distance GEMM + argmin ----
// Round-11: operands load DIRECTLY global->VGPR as contiguous 1KB frag
// blocks (base + lane*16B). No staging LDS, no barriers in the K-loop, no
// vmcnt drains; waves fully desynchronized, 12 waves/CU hide L2 latency.
// Pipe floors: MFMA ~25us, L2 1.07GB ~31us, HBM ~40MB ~6us.
// grid 2048: pt = blk&255, ct = blk>>8 -> 8 ct-siblings of a pt share one
// XCD's L2 (X fetched from HBM ~once); EF (1MB) L2-resident everywhere.
__launch_bounds__(256, 3)
__global__ void k_dist(const short* __restrict__ Xh, const short* __restrict__ Xl,
                       const short* __restrict__ Eh, const short* __restrict__ El,
                       const float* __restrict__ e2, unsigned long long* __restrict__ win) {
    __shared__ float sv[2][128];
    __shared__ int   si[2][128];

    const int tid = threadIdx.x;
    const int pt = blockIdx.x & 255;
    const int ct = blockIdx.x >> 8;
    const int n0 = pt * 128;
    const int c0 = ct * 128;

    const int w = tid >> 6, lane = tid & 63;
    const int wr = w >> 1, wc = w & 1;              // wave covers pts wr*64, codes wc*64
    const int m16 = lane & 15, quad = lane >> 4;

    f32x4 acc[4][4];
    #pragma unroll
    for (int i = 0; i < 4; ++i)
        #pragma unroll
        for (int j = 0; j < 4; ++j) acc[i][j] = (f32x4){0.f, 0.f, 0.f, 0.f};

    // per-(n-block) frag bases: 64 rows x 256 c = 16384 shorts; frag stride
    // within: t*2048 + i*512; lane offset lane*8 shorts = 16B.
    const short* Ahb = Xh + (pt * 2 + wr) * 16384 + lane * 8;
    const short* Alb = Xl + (pt * 2 + wr) * 16384 + lane * 8;
    const short* Bhb = Eh + (ct * 2 + wc) * 16384 + lane * 8;
    const short* Blb = El + (ct * 2 + wc) * 16384 + lane * 8;

    for (int t = 0; t < 8; ++t) {
        const int to = t * 2048;
        short8 ah[4], al[4], bh[4], bl[4];
        #pragma unroll
        for (int i = 0; i < 4; ++i) {
            ah[i] = *reinterpret_cast<const short8*>(Ahb + to + i * 512);
            al[i] = *reinterpret_cast<const short8*>(Alb + to + i * 512);
        }
        #pragma unroll
        for (int j = 0; j < 4; ++j) {
            bh[j] = *reinterpret_cast<const short8*>(Bhb + to + j * 512);
            bl[j] = *reinterpret_cast<const short8*>(Blb + to + j * 512);
        }
        __builtin_amdgcn_s_setprio(1);
        #pragma unroll
        for (int i = 0; i < 4; ++i)
            #pragma unroll
            for (int j = 0; j < 4; ++j)
                acc[i][j] = __builtin_amdgcn_mfma_f32_16x16x32_bf16(ah[i], bh[j], acc[i][j], 0, 0, 0);
        #pragma unroll
        for (int i = 0; i < 4; ++i)
            #pragma unroll
            for (int j = 0; j < 4; ++j)
                acc[i][j] = __builtin_amdgcn_mfma_f32_16x16x32_bf16(al[i], bh[j], acc[i][j], 0, 0, 0);
        #pragma unroll
        for (int i = 0; i < 4; ++i)
            #pragma unroll
            for (int j = 0; j < 4; ++j)
                acc[i][j] = __builtin_amdgcn_mfma_f32_16x16x32_bf16(ah[i], bl[j], acc[i][j], 0, 0, 0);
        __builtin_amdgcn_s_setprio(0);
    }

    // dist = e2[code] - 2*dot ; C/D layout: col=lane&15 (code), row=quad*4+reg (pt)
    float ecol[4];
    #pragma unroll
    for (int j = 0; j < 4; ++j) ecol[j] = e2[c0 + wc * 64 + j * 16 + m16];

    #pragma unroll
    for (int i = 0; i < 4; ++i) {
        #pragma unroll
        for (int rr = 0; rr < 4; ++rr) {
            float best = 3.4e38f; int bi = 0;
            #pragma unroll
            for (int j = 0; j < 4; ++j) {           // j ascending -> code ascending
                float d = fmaf(-2.f, acc[i][j][rr], ecol[j]);
                int code = c0 + wc * 64 + j * 16 + m16;
                if (d < best) { best = d; bi = code; }
            }
            #pragma unroll
            for (int m = 1; m < 16; m <<= 1) {      // 16 lanes hold 16 codes of this pt
                float ov = __shfl_xor(best, m);
                int   oi = __shfl_xor(bi, m);
                if (ov < best || (ov == best && oi < bi)) { best = ov; bi = oi; }
            }
            if (m16 == 0) {
                int p = wr * 64 + i * 16 + quad * 4 + rr;
                sv[wc][p] = best; si[wc][p] = bi;
            }
        }
    }
    __syncthreads();
    if (tid < 128) {
        float v0 = sv[0][tid]; int i0 = si[0][tid];
        float v1 = sv[1][tid]; int i1 = si[1][tid];
        if (v1 < v0) { v0 = v1; i0 = i1; }          // tie -> wc0 = smaller codes
        atomicMin(win + n0 + tid, pack_di(v0, i0)); // global argmin, no round-trip
    }
}

// ---- output: gather winner rows + write q/st/idx. grid 2048 (c-half split). ----
__global__ void k_out(const float* __restrict__ z, const float* __restrict__ emb,
                      const unsigned long long* __restrict__ win,
                      float* __restrict__ out) {
    __shared__ float Q[32][129];                    // [hw_local][c_half], 16.5KB
    __shared__ int sbi[32];
    int blk = blockIdx.x;
    int n0 = (blk >> 1) * 32;
    int ch = blk & 1;                               // c in [ch*128, ch*128+128)
    int tid = threadIdx.x;
    if (tid < 32) {
        int n = n0 + tid;
        int bi = (int)(unsigned)(win[n] & 0xFFFFFFFFull);
        sbi[tid] = bi;
        if (ch == 0) out[2 * QSZ + n] = (float)bi;  // idx as float
    }
    __syncthreads();
    {   // gather: 8 lanes x float4 x 4 j cover the 512B half-row per point
        int pt = tid >> 3, co = tid & 7;
        const float* ep = emb + sbi[pt] * DIM + ch * 128;
        #pragma unroll
        for (int j = 0; j < 4; ++j) {
            int c = j * 32 + co * 4;
            float4 v = *reinterpret_cast<const float4*>(ep + c);
            Q[pt][c] = v.x; Q[pt][c + 1] = v.y; Q[pt][c + 2] = v.z; Q[pt][c + 3] = v.w;
        }
    }
    __syncthreads();
    int hq = tid & 7, cr = tid >> 3;                // 8x16B = 128B runs per c-row
    int b = n0 >> 10, hw0 = (n0 & 1023) + hq * 4;
    #pragma unroll
    for (int it = 0; it < 4; ++it) {
        int cl = it * 32 + cr;                      // local c within half
        int c  = ch * 128 + cl;
        int off = b * CHW + c * HWSZ + hw0;
        float4 zv = *reinterpret_cast<const float4*>(z + off);
        float4 q = make_float4(Q[hq * 4 + 0][cl], Q[hq * 4 + 1][cl],
                               Q[hq * 4 + 2][cl], Q[hq * 4 + 3][cl]);
        *reinterpret_cast<float4*>(out + off) = q;
        float4 st = make_float4((q.x - zv.x) + zv.x, (q.y - zv.y) + zv.y,
                                (q.z - zv.z) + zv.z, (q.w - zv.w) + zv.w);
        *reinterpret_cast<float4*>(out + QSZ + off) = st;
    }
}

extern "C" void kernel_launch(void* const* d_in, const int* in_sizes, int n_in,
                              void* d_out, int out_size, void* d_ws, size_t ws_size,
                              hipStream_t stream) {
    const float* z   = (const float*)d_in[0];
    const float* emb = (const float*)d_in[1];
    float* out = (float*)d_out;
    float* ws  = (float*)d_ws;

    // ws layout (floats): Eh[0,131072) El[131072,262144) e2[262144,263168)
    //                     win[263168, 263168+65536) as u64 (256KB, 8B-aligned)
    short* Eh   = (short*)ws;
    short* El   = (short*)(ws + 131072);
    float* e2   = ws + 262144;
    unsigned long long* win = (unsigned long long*)(ws + 263168);

    // big X arrays live in d_out's q/st region (fully overwritten by k_out later)
    short* Xh = (short*)out;                 // 16.8 MB
    short* Xl = (short*)(out + 4194304);     // 16.8 MB

    hipLaunchKernelGGL(k_prep, dim3(2304), dim3(256), 0, stream, z, emb, Xh, Xl, Eh, El, e2, win);
    hipLaunchKernelGGL(k_dist, dim3(2048), dim3(256), 0, stream, Xh, Xl, Eh, El, e2, win);
    hipLaunchKernelGGL(k_out,  dim3(2048), dim3(256), 0, stream, z, emb, win, out);
}